// Round 1
// baseline (499.412 us; speedup 1.0000x reference)
//
#include <hip/hip_runtime.h>
#include <math.h>

// ---------------- CSR build ----------------

__global__ void k_deg(const int* __restrict__ col, int E, int* __restrict__ deg) {
    int e = blockIdx.x * blockDim.x + threadIdx.x;
    if (e < E) atomicAdd(&deg[col[e]], 1);
}

__global__ void k_dinv(const int* __restrict__ deg, int N, float* __restrict__ dinv) {
    int i = blockIdx.x * blockDim.x + threadIdx.x;
    if (i < N) dinv[i] = rsqrtf((float)(deg[i] + 1));  // +1 self loop
}

__global__ void k_blocksum(const int* __restrict__ cnt, int N, int* __restrict__ bsum) {
    __shared__ int s[256];
    int i = blockIdx.x * 256 + threadIdx.x;
    s[threadIdx.x] = (i < N) ? cnt[i] : 0;
    __syncthreads();
    for (int o = 128; o > 0; o >>= 1) {
        if (threadIdx.x < o) s[threadIdx.x] += s[threadIdx.x + o];
        __syncthreads();
    }
    if (threadIdx.x == 0) bsum[blockIdx.x] = s[0];
}

// single block, nb <= 256: in-place exclusive scan
__global__ void k_scan_bsum(int* __restrict__ bsum, int nb) {
    __shared__ int s[256];
    int v = (threadIdx.x < nb) ? bsum[threadIdx.x] : 0;
    s[threadIdx.x] = v;
    __syncthreads();
    for (int o = 1; o < 256; o <<= 1) {
        int t = (threadIdx.x >= o) ? s[threadIdx.x - o] : 0;
        __syncthreads();
        s[threadIdx.x] += t;
        __syncthreads();
    }
    if (threadIdx.x < nb) bsum[threadIdx.x] = s[threadIdx.x] - v;
}

__global__ void k_offsets(const int* __restrict__ cnt, int N, const int* __restrict__ bsum,
                          int* __restrict__ offs, int* __restrict__ cursor) {
    __shared__ int s[256];
    int i = blockIdx.x * 256 + threadIdx.x;
    int v = (i < N) ? cnt[i] : 0;
    s[threadIdx.x] = v;
    __syncthreads();
    for (int o = 1; o < 256; o <<= 1) {
        int t = (threadIdx.x >= o) ? s[threadIdx.x - o] : 0;
        __syncthreads();
        s[threadIdx.x] += t;
        __syncthreads();
    }
    if (i < N) {
        int off = bsum[blockIdx.x] + s[threadIdx.x] - v;  // exclusive prefix
        offs[i] = off;
        cursor[i] = off;
    }
}

__global__ void k_scatter(const int* __restrict__ row, const int* __restrict__ col, int E,
                          int* __restrict__ cursor, int* __restrict__ csr) {
    int e = blockIdx.x * blockDim.x + threadIdx.x;
    if (e < E) {
        int c = col[e];
        int p = atomicAdd(&cursor[c], 1);
        csr[p] = row[e];
    }
}

// graph boundaries via binary search (batch_index is sorted)
__global__ void k_bounds(const int* __restrict__ batch, int N, int Gn,
                         int* __restrict__ gstart, int* __restrict__ gcnt) {
    int g = blockIdx.x * blockDim.x + threadIdx.x;
    if (g >= Gn) return;
    int lo = 0, hi = N;
    while (lo < hi) { int m = (lo + hi) >> 1; if (batch[m] < g) lo = m + 1; else hi = m; }
    int s = lo;
    lo = 0; hi = N;
    while (lo < hi) { int m = (lo + hi) >> 1; if (batch[m] < g + 1) lo = m + 1; else hi = m; }
    gstart[g] = s;
    gcnt[g] = lo - s;
}

// ---------------- GEMM: G = (X @ W) * dinv[row], row-scaled ----------------
// X: [N,K], W: [K,64], out G: [N,64]. Block = 256 thr (4 waves), 32 nodes/block.
template <int K>
__global__ __launch_bounds__(256) void k_gemm(const float* __restrict__ X,
                                              const float* __restrict__ W,
                                              const float* __restrict__ dinv,
                                              float* __restrict__ Gb, int N) {
    __shared__ __align__(16) float Wl[K * 64];
    __shared__ __align__(16) float Xl[32 * (K + 4)];  // +4 pad: bank-conflict-free node reads

    for (int i = threadIdx.x; i < K * 64; i += 256) Wl[i] = W[i];

    const int wave = threadIdx.x >> 6;
    const int lane = threadIdx.x & 63;
    const int d4 = lane & 15;   // dim quad: dims [4*d4, 4*d4+4)
    const int ns = lane >> 4;   // node sub 0..3

    int base = blockIdx.x * 32;
    if (base >= N) return;
    int tile_n = N - base; if (tile_n > 32) tile_n = 32;

    __syncthreads();
    // stage X tile
    for (int idx = threadIdx.x; idx < 32 * (K / 4); idx += 256) {
        int n = idx / (K / 4);
        int kq = idx % (K / 4);
        float4 v = make_float4(0.f, 0.f, 0.f, 0.f);
        if (n < tile_n) v = ((const float4*)(X + (size_t)(base + n) * K))[kq];
        ((float4*)&Xl[n * (K + 4)])[kq] = v;
    }
    __syncthreads();

    const int n0 = wave * 8 + ns;  // local nodes n0 and n0+4
    const int n1 = n0 + 4;
    const float* xr0 = &Xl[n0 * (K + 4)];
    const float* xr1 = &Xl[n1 * (K + 4)];
    float a0x = 0, a0y = 0, a0z = 0, a0w = 0;
    float a1x = 0, a1y = 0, a1z = 0, a1w = 0;
#pragma unroll 16
    for (int k = 0; k < K; k++) {
        const float4 w4 = *(const float4*)&Wl[k * 64 + 4 * d4];
        const float xa = xr0[k];
        const float xb = xr1[k];
        a0x = fmaf(xa, w4.x, a0x); a0y = fmaf(xa, w4.y, a0y);
        a0z = fmaf(xa, w4.z, a0z); a0w = fmaf(xa, w4.w, a0w);
        a1x = fmaf(xb, w4.x, a1x); a1y = fmaf(xb, w4.y, a1y);
        a1z = fmaf(xb, w4.z, a1z); a1w = fmaf(xb, w4.w, a1w);
    }
    int gn0 = base + n0, gn1 = base + n1;
    if (gn0 < N) {
        float s = dinv[gn0];
        float4 o = make_float4(a0x * s, a0y * s, a0z * s, a0w * s);
        ((float4*)(Gb + (size_t)gn0 * 64))[d4] = o;
    }
    if (gn1 < N) {
        float s = dinv[gn1];
        float4 o = make_float4(a1x * s, a1y * s, a1z * s, a1w * s);
        ((float4*)(Gb + (size_t)gn1 * 64))[d4] = o;
    }
}

// ---------------- Aggregate: H[i] = tanh(dinv[i]*(G[i] + sum_{e in(i)} G[src_e]) + b) ----------------
__global__ __launch_bounds__(256) void k_agg(const float* __restrict__ Gb,
                                             const int* __restrict__ offs,
                                             const int* __restrict__ ends,
                                             const int* __restrict__ csr,
                                             const float* __restrict__ dinv,
                                             const float* __restrict__ bias,
                                             float* __restrict__ H, int N) {
    int n = blockIdx.x * 4 + (threadIdx.x >> 6);
    if (n >= N) return;
    int lane = threadIdx.x & 63;
    float acc = Gb[(size_t)n * 64 + lane];
    float acc2 = 0.f;
    int s = offs[n], e = ends[n];
    int i = s;
    for (; i + 1 < e; i += 2) {
        int s0 = csr[i], s1 = csr[i + 1];
        acc += Gb[(size_t)s0 * 64 + lane];
        acc2 += Gb[(size_t)s1 * 64 + lane];
    }
    if (i < e) acc += Gb[(size_t)csr[i] * 64 + lane];
    acc += acc2;
    H[(size_t)n * 64 + lane] = tanhf(acc * dinv[n] + bias[lane]);
}

// ---------------- Pool + output head ----------------
__global__ __launch_bounds__(64) void k_pool(const float* __restrict__ H,
                                             const int* __restrict__ gstart,
                                             const int* __restrict__ gcnt,
                                             const float* __restrict__ Wout,
                                             const float* __restrict__ bout,
                                             float* __restrict__ out,
                                             float* __restrict__ hidden) {
    int g = blockIdx.x;
    int lane = threadIdx.x;  // 0..63, dim
    int s = gstart[g], c = gcnt[g];
    float vmax = -INFINITY, vsum = 0.f;
    for (int n = s; n < s + c; n++) {
        float v = H[(size_t)n * 64 + lane];
        vmax = fmaxf(vmax, v);
        vsum += v;
    }
    float gmax = (c > 0) ? vmax : 0.f;              // tanh output is always finite
    float gmean = (c > 0) ? vsum / (float)c : 0.f;  // cnt>=1 clamp
    hidden[(size_t)g * 128 + lane] = gmax;
    hidden[(size_t)g * 128 + 64 + lane] = gmean;
    float p = fmaf(gmax, Wout[lane], gmean * Wout[64 + lane]);
    for (int o = 32; o > 0; o >>= 1) p += __shfl_down(p, o);
    if (lane == 0) out[g] = p + bout[0];
}

// ---------------- launch ----------------
extern "C" void kernel_launch(void* const* d_in, const int* in_sizes, int n_in,
                              void* d_out, int out_size, void* d_ws, size_t ws_size,
                              hipStream_t stream) {
    const float* x    = (const float*)d_in[0];
    const int*   ei   = (const int*)d_in[1];
    const int*   batch= (const int*)d_in[2];
    const float* W0 = (const float*)d_in[3];  const float* b0 = (const float*)d_in[4];
    const float* W1 = (const float*)d_in[5];  const float* b1 = (const float*)d_in[6];
    const float* W2 = (const float*)d_in[7];  const float* b2 = (const float*)d_in[8];
    const float* W3 = (const float*)d_in[9];  const float* b3 = (const float*)d_in[10];
    const float* Wout = (const float*)d_in[11]; const float* bout = (const float*)d_in[12];

    const int N  = in_sizes[2];
    const int E  = in_sizes[1] / 2;
    const int Gn = out_size / 129;  // out [G] + hidden [G,128]

    const int* row = ei;       // source
    const int* col = ei + E;   // target

    float* out_p    = (float*)d_out;
    float* hidden_p = out_p + Gn;

    // workspace carve-up (256B aligned)
    char* wp = (char*)d_ws;
    auto alloc = [&](size_t bytes) { void* p = (void*)wp; wp += (bytes + 255) & ~(size_t)255; return p; };
    int*   deg    = (int*)alloc((size_t)N * 4);
    float* dinv   = (float*)alloc((size_t)N * 4);
    int*   offs   = (int*)alloc((size_t)N * 4);
    int*   cursor = (int*)alloc((size_t)N * 4);
    int*   bsum   = (int*)alloc(256 * 4);
    int*   csr    = (int*)alloc((size_t)E * 4);
    int*   gstart = (int*)alloc((size_t)Gn * 4);
    int*   gcnt   = (int*)alloc((size_t)Gn * 4);
    float* Gbuf   = (float*)alloc((size_t)N * 64 * 4);
    float* Ha     = (float*)alloc((size_t)N * 64 * 4);
    float* Hb     = (float*)alloc((size_t)N * 64 * 4);

    hipMemsetAsync(deg, 0, (size_t)N * 4, stream);

    k_deg<<<(E + 255) / 256, 256, 0, stream>>>(col, E, deg);
    k_dinv<<<(N + 255) / 256, 256, 0, stream>>>(deg, N, dinv);
    int nb = (N + 255) / 256;
    k_blocksum<<<nb, 256, 0, stream>>>(deg, N, bsum);
    k_scan_bsum<<<1, 256, 0, stream>>>(bsum, nb);
    k_offsets<<<nb, 256, 0, stream>>>(deg, N, bsum, offs, cursor);
    k_scatter<<<(E + 255) / 256, 256, 0, stream>>>(row, col, E, cursor, csr);
    k_bounds<<<(Gn + 255) / 256, 256, 0, stream>>>(batch, N, Gn, gstart, gcnt);

    const int gblocks = (N + 31) / 32;
    const int ablocks = (N + 3) / 4;

    k_gemm<128><<<gblocks, 256, 0, stream>>>(x, W0, dinv, Gbuf, N);
    k_agg<<<ablocks, 256, 0, stream>>>(Gbuf, offs, cursor, csr, dinv, b0, Ha, N);
    k_gemm<64><<<gblocks, 256, 0, stream>>>(Ha, W1, dinv, Gbuf, N);
    k_agg<<<ablocks, 256, 0, stream>>>(Gbuf, offs, cursor, csr, dinv, b1, Hb, N);
    k_gemm<64><<<gblocks, 256, 0, stream>>>(Hb, W2, dinv, Gbuf, N);
    k_agg<<<ablocks, 256, 0, stream>>>(Gbuf, offs, cursor, csr, dinv, b2, Ha, N);
    k_gemm<64><<<gblocks, 256, 0, stream>>>(Ha, W3, dinv, Gbuf, N);
    k_agg<<<ablocks, 256, 0, stream>>>(Gbuf, offs, cursor, csr, dinv, b3, Hb, N);

    k_pool<<<Gn, 64, 0, stream>>>(Hb, gstart, gcnt, Wout, bout, out_p, hidden_p);
}

// Round 2
// 413.212 us; speedup vs baseline: 1.2086x; 1.2086x over previous
//
#include <hip/hip_runtime.h>
#include <math.h>

// ---------------- CSR build ----------------

__global__ void k_deg(const int* __restrict__ col, int E, int* __restrict__ deg) {
    int t = blockIdx.x * blockDim.x + threadIdx.x;
    int e0 = t * 4;
    if (e0 + 3 < E) {
        int4 c = *(const int4*)(col + e0);
        atomicAdd(&deg[c.x], 1); atomicAdd(&deg[c.y], 1);
        atomicAdd(&deg[c.z], 1); atomicAdd(&deg[c.w], 1);
    } else {
        for (int e = e0; e < E; e++) atomicAdd(&deg[col[e]], 1);
    }
}

__global__ void k_blocksum(const int* __restrict__ cnt, int N, int* __restrict__ bsum) {
    __shared__ int s[256];
    int i = blockIdx.x * 256 + threadIdx.x;
    s[threadIdx.x] = (i < N) ? cnt[i] : 0;
    __syncthreads();
    for (int o = 128; o > 0; o >>= 1) {
        if (threadIdx.x < o) s[threadIdx.x] += s[threadIdx.x + o];
        __syncthreads();
    }
    if (threadIdx.x == 0) bsum[blockIdx.x] = s[0];
}

// single block, nb <= 256: in-place exclusive scan
__global__ void k_scan_bsum(int* __restrict__ bsum, int nb) {
    __shared__ int s[256];
    int v = (threadIdx.x < nb) ? bsum[threadIdx.x] : 0;
    s[threadIdx.x] = v;
    __syncthreads();
    for (int o = 1; o < 256; o <<= 1) {
        int t = (threadIdx.x >= o) ? s[threadIdx.x - o] : 0;
        __syncthreads();
        s[threadIdx.x] += t;
        __syncthreads();
    }
    if (threadIdx.x < nb) bsum[threadIdx.x] = s[threadIdx.x] - v;
}

// offsets + cursor + dinv in one pass
__global__ void k_offsets(const int* __restrict__ cnt, int N, const int* __restrict__ bsum,
                          int* __restrict__ offs, int* __restrict__ cursor,
                          float* __restrict__ dinv) {
    __shared__ int s[256];
    int i = blockIdx.x * 256 + threadIdx.x;
    int v = (i < N) ? cnt[i] : 0;
    s[threadIdx.x] = v;
    __syncthreads();
    for (int o = 1; o < 256; o <<= 1) {
        int t = (threadIdx.x >= o) ? s[threadIdx.x - o] : 0;
        __syncthreads();
        s[threadIdx.x] += t;
        __syncthreads();
    }
    if (i < N) {
        int off = bsum[blockIdx.x] + s[threadIdx.x] - v;  // exclusive prefix
        offs[i] = off;
        cursor[i] = off;
        dinv[i] = rsqrtf((float)(v + 1));  // +1 self loop
    }
}

__global__ void k_scatter(const int* __restrict__ row, const int* __restrict__ col, int E,
                          int* __restrict__ cursor, int* __restrict__ csr) {
    int e = blockIdx.x * blockDim.x + threadIdx.x;
    if (e < E) {
        int c = col[e];
        int p = atomicAdd(&cursor[c], 1);
        csr[p] = row[e];
    }
}

// ---------------- GEMM: G = (X @ W) * dinv[row] ----------------
// X: [N,K], W: [K,64], out G: [N,64]. Block = 256 thr, 64 nodes/block.
// Per-thread tile: 2 nodes x 8 dims -> 16 FMA per (2x ds_read_b128 + 2x ds_read_b32).
template <int K>
__global__ __launch_bounds__(256) void k_gemm(const float* __restrict__ X,
                                              const float* __restrict__ W,
                                              const float* __restrict__ dinv,
                                              float* __restrict__ Gb, int N) {
    constexpr int PITCH = K + 4;  // /4 -> 16B-aligned rows; %32==4 -> conflict-free x reads
    __shared__ __align__(16) float Wl[K * 64];
    __shared__ __align__(16) float Xl[64 * PITCH];

    for (int i = threadIdx.x; i < K * 16; i += 256) ((float4*)Wl)[i] = ((const float4*)W)[i];

    const int wave = threadIdx.x >> 6;
    const int lane = threadIdx.x & 63;
    const int d8 = lane & 7;    // dim group: dims [8*d8, 8*d8+8)
    const int ns = lane >> 3;   // node sub 0..7

    int base = blockIdx.x * 64;
    if (base >= N) return;
    int tile_n = N - base; if (tile_n > 64) tile_n = 64;

    // stage X tile (fully coalesced: linear over the X block)
    for (int idx = threadIdx.x; idx < 64 * (K / 4); idx += 256) {
        int n = idx / (K / 4);
        int kq = idx % (K / 4);
        float4 v = make_float4(0.f, 0.f, 0.f, 0.f);
        if (n < tile_n) v = ((const float4*)(X + (size_t)(base + n) * K))[kq];
        ((float4*)&Xl[n * PITCH])[kq] = v;
    }
    __syncthreads();

    const int n0 = wave * 16 + ns;  // local nodes n0 and n0+8
    const int n1 = n0 + 8;
    const float* xr0 = &Xl[n0 * PITCH];
    const float* xr1 = &Xl[n1 * PITCH];
    const float* wcol = &Wl[d8 * 8];
    float4 a0l = make_float4(0,0,0,0), a0h = make_float4(0,0,0,0);
    float4 a1l = make_float4(0,0,0,0), a1h = make_float4(0,0,0,0);
#pragma unroll 8
    for (int k = 0; k < K; k++) {
        const float4 wa = *(const float4*)&wcol[k * 64];
        const float4 wb = *(const float4*)&wcol[k * 64 + 4];
        const float xa = xr0[k];
        const float xb = xr1[k];
        a0l.x = fmaf(xa, wa.x, a0l.x); a0l.y = fmaf(xa, wa.y, a0l.y);
        a0l.z = fmaf(xa, wa.z, a0l.z); a0l.w = fmaf(xa, wa.w, a0l.w);
        a0h.x = fmaf(xa, wb.x, a0h.x); a0h.y = fmaf(xa, wb.y, a0h.y);
        a0h.z = fmaf(xa, wb.z, a0h.z); a0h.w = fmaf(xa, wb.w, a0h.w);
        a1l.x = fmaf(xb, wa.x, a1l.x); a1l.y = fmaf(xb, wa.y, a1l.y);
        a1l.z = fmaf(xb, wa.z, a1l.z); a1l.w = fmaf(xb, wa.w, a1l.w);
        a1h.x = fmaf(xb, wb.x, a1h.x); a1h.y = fmaf(xb, wb.y, a1h.y);
        a1h.z = fmaf(xb, wb.z, a1h.z); a1h.w = fmaf(xb, wb.w, a1h.w);
    }
    int gn0 = base + n0, gn1 = base + n1;
    if (gn0 < N) {
        float s = dinv[gn0];
        float4* p = (float4*)(Gb + (size_t)gn0 * 64);
        p[d8 * 2]     = make_float4(a0l.x * s, a0l.y * s, a0l.z * s, a0l.w * s);
        p[d8 * 2 + 1] = make_float4(a0h.x * s, a0h.y * s, a0h.z * s, a0h.w * s);
    }
    if (gn1 < N) {
        float s = dinv[gn1];
        float4* p = (float4*)(Gb + (size_t)gn1 * 64);
        p[d8 * 2]     = make_float4(a1l.x * s, a1l.y * s, a1l.z * s, a1l.w * s);
        p[d8 * 2 + 1] = make_float4(a1h.x * s, a1h.y * s, a1h.z * s, a1h.w * s);
    }
}

// ---------------- Aggregate: H[i] = tanh(dinv[i]*(G[i] + sum_{e in(i)} G[src_e]) + b) ----------------
// 4 independent accumulators -> 4 gathers in flight per wave (MLP).
__global__ __launch_bounds__(256) void k_agg(const float* __restrict__ Gb,
                                             const int* __restrict__ offs,
                                             const int* __restrict__ ends,
                                             const int* __restrict__ csr,
                                             const float* __restrict__ dinv,
                                             const float* __restrict__ bias,
                                             float* __restrict__ H, int N) {
    int n = blockIdx.x * 4 + (threadIdx.x >> 6);
    if (n >= N) return;
    int lane = threadIdx.x & 63;
    int s = offs[n], e = ends[n];
    float a0 = Gb[(size_t)n * 64 + lane];
    float a1 = 0.f, a2 = 0.f, a3 = 0.f;
    int i = s;
    for (; i + 3 < e; i += 4) {
        int i0 = csr[i], i1 = csr[i + 1], i2 = csr[i + 2], i3 = csr[i + 3];
        float g0 = Gb[(size_t)i0 * 64 + lane];
        float g1 = Gb[(size_t)i1 * 64 + lane];
        float g2 = Gb[(size_t)i2 * 64 + lane];
        float g3 = Gb[(size_t)i3 * 64 + lane];
        a0 += g0; a1 += g1; a2 += g2; a3 += g3;
    }
    if (i + 1 < e) {
        int i0 = csr[i], i1 = csr[i + 1];
        a0 += Gb[(size_t)i0 * 64 + lane];
        a1 += Gb[(size_t)i1 * 64 + lane];
        i += 2;
    }
    if (i < e) a2 += Gb[(size_t)csr[i] * 64 + lane];
    float acc = (a0 + a1) + (a2 + a3);
    H[(size_t)n * 64 + lane] = tanhf(acc * dinv[n] + bias[lane]);
}

// ---------------- Pool + output head (bounds folded in) ----------------
__global__ __launch_bounds__(64) void k_pool(const float* __restrict__ H,
                                             const int* __restrict__ batch, int N,
                                             const float* __restrict__ Wout,
                                             const float* __restrict__ bout,
                                             float* __restrict__ out,
                                             float* __restrict__ hidden) {
    int g = blockIdx.x;
    int lane = threadIdx.x;  // 0..63, dim
    // binary-search graph bounds (batch sorted)
    int lo = 0, hi = N;
    while (lo < hi) { int m = (lo + hi) >> 1; if (batch[m] < g) lo = m + 1; else hi = m; }
    int s = lo;
    lo = s; hi = N;
    while (lo < hi) { int m = (lo + hi) >> 1; if (batch[m] < g + 1) lo = m + 1; else hi = m; }
    int c = lo - s;

    float m0 = -INFINITY, m1 = -INFINITY, m2 = -INFINITY, m3 = -INFINITY;
    float s0 = 0.f, s1 = 0.f, s2 = 0.f, s3 = 0.f;
    int n = s;
    for (; n + 3 < s + c; n += 4) {
        float v0 = H[(size_t)n * 64 + lane];
        float v1 = H[(size_t)(n + 1) * 64 + lane];
        float v2 = H[(size_t)(n + 2) * 64 + lane];
        float v3 = H[(size_t)(n + 3) * 64 + lane];
        m0 = fmaxf(m0, v0); s0 += v0;
        m1 = fmaxf(m1, v1); s1 += v1;
        m2 = fmaxf(m2, v2); s2 += v2;
        m3 = fmaxf(m3, v3); s3 += v3;
    }
    for (; n < s + c; n++) {
        float v = H[(size_t)n * 64 + lane];
        m0 = fmaxf(m0, v); s0 += v;
    }
    float vmax = fmaxf(fmaxf(m0, m1), fmaxf(m2, m3));
    float vsum = (s0 + s1) + (s2 + s3);
    float gmax = (c > 0) ? vmax : 0.f;
    float gmean = (c > 0) ? vsum / (float)c : 0.f;
    hidden[(size_t)g * 128 + lane] = gmax;
    hidden[(size_t)g * 128 + 64 + lane] = gmean;
    float p = fmaf(gmax, Wout[lane], gmean * Wout[64 + lane]);
    for (int o = 32; o > 0; o >>= 1) p += __shfl_down(p, o);
    if (lane == 0) out[g] = p + bout[0];
}

// ---------------- launch ----------------
extern "C" void kernel_launch(void* const* d_in, const int* in_sizes, int n_in,
                              void* d_out, int out_size, void* d_ws, size_t ws_size,
                              hipStream_t stream) {
    const float* x    = (const float*)d_in[0];
    const int*   ei   = (const int*)d_in[1];
    const int*   batch= (const int*)d_in[2];
    const float* W0 = (const float*)d_in[3];  const float* b0 = (const float*)d_in[4];
    const float* W1 = (const float*)d_in[5];  const float* b1 = (const float*)d_in[6];
    const float* W2 = (const float*)d_in[7];  const float* b2 = (const float*)d_in[8];
    const float* W3 = (const float*)d_in[9];  const float* b3 = (const float*)d_in[10];
    const float* Wout = (const float*)d_in[11]; const float* bout = (const float*)d_in[12];

    const int N  = in_sizes[2];
    const int E  = in_sizes[1] / 2;
    const int Gn = out_size / 129;  // out [G] + hidden [G,128]

    const int* row = ei;       // source
    const int* col = ei + E;   // target

    float* out_p    = (float*)d_out;
    float* hidden_p = out_p + Gn;

    // workspace carve-up (256B aligned)
    char* wp = (char*)d_ws;
    auto alloc = [&](size_t bytes) { void* p = (void*)wp; wp += (bytes + 255) & ~(size_t)255; return p; };
    int*   deg    = (int*)alloc((size_t)N * 4);
    float* dinv   = (float*)alloc((size_t)N * 4);
    int*   offs   = (int*)alloc((size_t)N * 4);
    int*   cursor = (int*)alloc((size_t)N * 4);
    int*   bsum   = (int*)alloc(256 * 4);
    int*   csr    = (int*)alloc((size_t)E * 4);
    float* Gbuf   = (float*)alloc((size_t)N * 64 * 4);
    float* Ha     = (float*)alloc((size_t)N * 64 * 4);
    float* Hb     = (float*)alloc((size_t)N * 64 * 4);

    hipMemsetAsync(deg, 0, (size_t)N * 4, stream);

    k_deg<<<(E / 4 + 255) / 256, 256, 0, stream>>>(col, E, deg);
    int nb = (N + 255) / 256;
    k_blocksum<<<nb, 256, 0, stream>>>(deg, N, bsum);
    k_scan_bsum<<<1, 256, 0, stream>>>(bsum, nb);
    k_offsets<<<nb, 256, 0, stream>>>(deg, N, bsum, offs, cursor, dinv);
    k_scatter<<<(E + 255) / 256, 256, 0, stream>>>(row, col, E, cursor, csr);

    const int gblocks = (N + 63) / 64;
    const int ablocks = (N + 3) / 4;

    k_gemm<128><<<gblocks, 256, 0, stream>>>(x, W0, dinv, Gbuf, N);
    k_agg<<<ablocks, 256, 0, stream>>>(Gbuf, offs, cursor, csr, dinv, b0, Ha, N);
    k_gemm<64><<<gblocks, 256, 0, stream>>>(Ha, W1, dinv, Gbuf, N);
    k_agg<<<ablocks, 256, 0, stream>>>(Gbuf, offs, cursor, csr, dinv, b1, Hb, N);
    k_gemm<64><<<gblocks, 256, 0, stream>>>(Hb, W2, dinv, Gbuf, N);
    k_agg<<<ablocks, 256, 0, stream>>>(Gbuf, offs, cursor, csr, dinv, b2, Ha, N);
    k_gemm<64><<<gblocks, 256, 0, stream>>>(Ha, W3, dinv, Gbuf, N);
    k_agg<<<ablocks, 256, 0, stream>>>(Gbuf, offs, cursor, csr, dinv, b3, Hb, N);

    k_pool<<<Gn, 64, 0, stream>>>(Hb, batch, N, Wout, bout, out_p, hidden_p);
}